// Round 19
// baseline (580.561 us; speedup 1.0000x reference)
//
#include <hip/hip_runtime.h>
#include <cstdint>
#include <cstddef>

#define NE 8
#define DMODEL 768
#define MLPDIM 3072
#define NDET 16384
#define NCLS 4096
#define NTOK 20480
#define ROWS_PER_E 5120   /* 16*256 (det) + 8*128 (cls) */
#define TOT_ROWS 40960

typedef float f32x4 __attribute__((ext_vector_type(4)));
typedef __bf16 bf16x8 __attribute__((ext_vector_type(8)));

__device__ __forceinline__ unsigned short f2bf(float f) {
    unsigned u = __float_as_uint(f);
    u += 0x7FFFu + ((u >> 16) & 1u);   // RNE
    return (unsigned short)(u >> 16);
}
__device__ __forceinline__ float bf2f(unsigned v) {
    return __uint_as_float(v << 16);
}
__device__ __forceinline__ float gelu_f(float x) {
    // jax.nn.gelu approximate=True. Exact identity: 0.5*(1+tanh(u)) == sigmoid(2u)
    // => gelu = x / (1 + exp(-2u)), u = 0.79788456*(x + 0.044715 x^3).
    float u = x * (0.7978845608028654f + 0.0356774081099f * x * x);
    return x * __frcp_rn(1.0f + __expf(-2.0f * u));
}

// async global->LDS, 16B per lane; dst is wave-uniform base, HW adds lane*16
__device__ __forceinline__ void gload16(const void* g, void* l) {
    __builtin_amdgcn_global_load_lds(
        (const __attribute__((address_space(1))) unsigned int*)g,
        (__attribute__((address_space(3))) unsigned int*)l, 16, 0, 0);
}

// ---------------- router (fp32) + x->bf16 conversion fused ----------------
__global__ void k_router(const float* __restrict__ xd, const float* __restrict__ xc,
                         const float* __restrict__ wrd, const float* __restrict__ wrc,
                         ushort* __restrict__ xbf,
                         int* __restrict__ e1, int* __restrict__ e2,
                         float* __restrict__ g1, float* __restrict__ g2) {
    int wave = threadIdx.x >> 6, lane = threadIdx.x & 63;
    int t = blockIdx.x * 4 + wave;
    if (t >= NTOK) return;
    const float* xrow;
    const float* w;
    if (t < NDET) { xrow = xd + (size_t)t * DMODEL; w = wrd; }
    else          { xrow = xc + (size_t)(t - NDET) * DMODEL; w = wrc; }
    ushort* xbrow = xbf + (size_t)t * DMODEL;
    float acc[8];
    #pragma unroll
    for (int e = 0; e < 8; e++) acc[e] = 0.0f;
    #pragma unroll
    for (int kk = 0; kk < DMODEL / 64; kk++) {
        int k = kk * 64 + lane;
        float xv = xrow[k];
        xbrow[k] = f2bf(xv);              // fused bf16 conversion
        const float* wr = w + k * 8;
        #pragma unroll
        for (int e = 0; e < 8; e++) acc[e] += xv * wr[e];
    }
    #pragma unroll
    for (int e = 0; e < 8; e++) {
        #pragma unroll
        for (int off = 32; off > 0; off >>= 1) acc[e] += __shfl_xor(acc[e], off);
    }
    // top-2 with lower-index tie-break (lax.top_k)
    int i1 = 0; float v1 = acc[0];
    #pragma unroll
    for (int e = 1; e < 8; e++) if (acc[e] > v1) { v1 = acc[e]; i1 = e; }
    int i2 = -1; float v2 = -1e30f;
    #pragma unroll
    for (int e = 0; e < 8; e++) if (e != i1 && acc[e] > v2) { v2 = acc[e]; i2 = e; }
    float Z = 0.0f;
    #pragma unroll
    for (int e = 0; e < 8; e++) Z += __expf(acc[e] - v1);
    if (lane == 0) {
        e1[t] = i1; e2[t] = i2;
        g1[t] = 1.0f / Z;
        g2[t] = __expf(v2 - v1) / Z;
    }
}

// ---------------- w [E][K][N] fp32 -> [E][N][K] bf16 (float4 loads) ----------------
__global__ void k_transpose_bf(const float* __restrict__ in, ushort* __restrict__ out,
                               int K, int N) {
    __shared__ float tile[32][33];
    int e = blockIdx.z;
    const float* A = in + (size_t)e * K * N;
    ushort* B = out + (size_t)e * N * K;
    int n0 = blockIdx.x * 32, k0 = blockIdx.y * 32;
    int tx = threadIdx.x, ty = threadIdx.y;   // (8,32)
    float4 v = *(const float4*)(A + (size_t)(k0 + ty) * N + n0 + tx * 4);
    tile[ty][tx * 4 + 0] = v.x; tile[ty][tx * 4 + 1] = v.y;
    tile[ty][tx * 4 + 2] = v.z; tile[ty][tx * 4 + 3] = v.w;
    __syncthreads();
    ushort4 o;
    o.x = f2bf(tile[tx * 4 + 0][ty]);
    o.y = f2bf(tile[tx * 4 + 1][ty]);
    o.z = f2bf(tile[tx * 4 + 2][ty]);
    o.w = f2bf(tile[tx * 4 + 3][ty]);
    *(ushort4*)(B + (size_t)(n0 + ty) * K + k0 + tx * 4) = o;
}

// ---------------- capacity scan: one wave per group, k-major order ----------------
__global__ void k_scan(const int* __restrict__ e1, const int* __restrict__ e2,
                       int* __restrict__ slot_map, int* __restrict__ r1, int* __restrict__ r2) {
    int g = blockIdx.x;          // 0..15 det, 16..23 cls
    int lane = threadIdx.x;      // 64 threads
    int S, C, base;
    if (g < 16) { S = 1024; C = 256; base = g * 1024; }
    else        { S = 512;  C = 128; base = NDET + (g - 16) * 512; }
    int cnt[8];
    #pragma unroll
    for (int e = 0; e < 8; e++) cnt[e] = 0;
    unsigned long long lower = (lane == 0) ? 0ULL : ((~0ULL) >> (64 - lane));
    int nch = (2 * S) >> 6;
    for (int ch = 0; ch < nch; ch++) {
        int n = ch * 64 + lane;
        int k = (n >= S) ? 1 : 0;
        int s = n - k * S;
        int tok = base + s;
        int e = k ? e2[tok] : e1[tok];
        int pos = 0;
        #pragma unroll
        for (int ee = 0; ee < 8; ee++) {
            unsigned long long m = __ballot(e == ee);
            if (e == ee) pos = cnt[ee] + __popcll(m & lower);
            cnt[ee] += __popcll(m);
        }
        int r = -1;
        if (pos < C) {
            int local = (g < 16) ? (g * 256 + pos) : (4096 + (g - 16) * 128 + pos);
            r = e * ROWS_PER_E + local;
            slot_map[r] = tok;
        }
        if (k == 0) r1[tok] = r; else r2[tok] = r;
    }
}

// ---------------- GEMM: BMx128 tile, BK=64, per-wave 64x64 ----------------
// R16 chassis (best: 567us) templated on BM:
//  - BM=128 (4 waves, 2x2): GEMM2 — bit-identical to R16's proven config.
//  - BM=256 (8 waves, 4x2): GEMM1 — halves block count so the ~33% per-block
//    prologue+epilogue overhead (12-K-tile loop) halves; staging drops to
//    6 gloads/wave/tile; (512,2) -> 16 waves/CU (~50% occ).
// Inner loop, swizzle (XOR-8, 0 conflicts measured), epilogue: unchanged.
// MFAST grouped m-fastest walk (A-group <= 4MB per-XCD L2) on both GEMMs.
// MODE 0: A = xbf gathered via slot_map -> h=gelu(A@B+b) (chunk-local rows)
// MODE 1: A = h (chunk-local) -> y[global row] = A@B+b
template<int BM, int KTOT, int NTOT, int MODE, bool MFAST>
__global__ __launch_bounds__(BM * 2, BM == 128 ? 4 : 2) void k_gemm(
    const ushort* __restrict__ Asrc, const int* __restrict__ slot_map,
    const ushort* __restrict__ wtBase, const float* __restrict__ biasBase,
    ushort* __restrict__ Cdst, int eBase, int gm) {
    constexpr int KT = KTOT / 64;            // 12 (GEMM1) / 48 (GEMM2)
    constexpr int NBN = NTOT / 128;
    constexpr int BROWS = 4096 / BM;         // B rows staged per wave: 32 / 16
    constexpr int NBG = BROWS / 8;           // B gloads per wave: 4 / 2
    __shared__ __align__(1024) ushort As[BM * 64];
    __shared__ __align__(1024) ushort Bs[128 * 64];

    // bijective XCD-chunked swizzle (gridDim.x % 8 == 0)
    const int q = gridDim.x >> 3;
    const int id2 = (blockIdx.x & 7) * q + (blockIdx.x >> 3);
    int mb, nb;
    if (MFAST) {
        // grouped m-fastest: group = gm consecutive mbs; within group, mb fastest
        int bpg = gm * NBN;
        int g = id2 / bpg, r = id2 - g * bpg;
        nb = r / gm;
        mb = g * gm + (r - nb * gm);
    } else {
        mb = id2 / NBN;
        nb = id2 - mb * NBN;
    }
    const int e = eBase + mb / (ROWS_PER_E / BM);
    const int m0 = mb * BM;                      // chunk-local row base
    const int rbase = eBase * ROWS_PER_E + m0;   // global expert-row base
    const int n0 = nb * 128;
    const ushort* Bt = wtBase + (size_t)e * KTOT * NTOT;
    const float* bias = biasBase + (size_t)e * NTOT;

    const int t = threadIdx.x, lane = t & 63, wave = t >> 6;
    const int g8 = lane >> 3;          // row within 8-row staging group
    const int p8 = lane & 7;           // physical 16B chunk this lane fills
    const int swz = ((p8 ^ g8) << 4);  // byte offset of LOGICAL chunk to fetch

    // staging: wave w covers A rows [w*32, w*32+32) and B rows [w*BROWS, ...)
    const char* aS[4];
    const char* bS[NBG];
    #pragma unroll
    for (int j = 0; j < 4; j++) {
        int r = wave * 32 + j * 8 + g8;
        size_t arow;
        if (MODE == 0) { int tk = slot_map[rbase + r]; arow = (size_t)(tk < 0 ? 0 : tk); }
        else           { arow = (size_t)(m0 + r); }
        aS[j] = (const char*)(Asrc + arow * KTOT) + swz;
    }
    #pragma unroll
    for (int j = 0; j < NBG; j++) {
        int r = wave * BROWS + j * 8 + g8;
        bS[j] = (const char*)(Bt + (size_t)(n0 + r) * KTOT) + swz;
    }

    auto ISSUE = [&](int kt) {
        size_t o = (size_t)kt * 128;   // 64 bf16 = 128 B per row per K-tile
        #pragma unroll
        for (int j = 0; j < 4; j++)
            gload16(aS[j] + o, As + (wave * 32 + j * 8) * 64);
        #pragma unroll
        for (int j = 0; j < NBG; j++)
            gload16(bS[j] + o, Bs + (wave * BROWS + j * 8) * 64);
    };

    const int wr = wave >> 1, wc = wave & 1;   // wave grid (BM/64)m x 2n, out 64x64
    const int l15 = lane & 15, kq = lane >> 4, l7 = lane & 7;
    const int ch[2] = { ((kq) ^ l7) << 3, ((4 + kq) ^ l7) << 3 };  // swizzled k-chunks

    f32x4 acc[4][4] = {};

    ISSUE(0);
    for (int ks = 0; ks < KT; ks++) {
        __syncthreads();               // drains vmcnt: tile ks visible in LDS
        // ---- kc = 0 ----
        bf16x8 af0[4], bf0[4];
        #pragma unroll
        for (int mi = 0; mi < 4; mi++)
            af0[mi] = *(const bf16x8*)(&As[(wr * 64 + mi * 16 + l15) * 64 + ch[0]]);
        #pragma unroll
        for (int nf = 0; nf < 4; nf++)
            bf0[nf] = *(const bf16x8*)(&Bs[(wc * 64 + nf * 16 + l15) * 64 + ch[0]]);
        __builtin_amdgcn_s_setprio(1);
        #pragma unroll
        for (int mi = 0; mi < 4; mi++) {
            #pragma unroll
            for (int nf = 0; nf < 4; nf++)
                acc[mi][nf] = __builtin_amdgcn_mfma_f32_16x16x32_bf16(
                    af0[mi], bf0[nf], acc[mi][nf], 0, 0, 0);
        }
        __builtin_amdgcn_s_setprio(0);
        // ---- kc = 1 ----
        bf16x8 af1[4], bf1[4];
        #pragma unroll
        for (int mi = 0; mi < 4; mi++)
            af1[mi] = *(const bf16x8*)(&As[(wr * 64 + mi * 16 + l15) * 64 + ch[1]]);
        #pragma unroll
        for (int nf = 0; nf < 4; nf++)
            bf1[nf] = *(const bf16x8*)(&Bs[(wc * 64 + nf * 16 + l15) * 64 + ch[1]]);
        __syncthreads();               // all waves done reading LDS tile ks
        if (ks + 1 < KT) ISSUE(ks + 1);   // loads fly under kc1 MFMA + other blocks
        __builtin_amdgcn_s_setprio(1);
        #pragma unroll
        for (int mi = 0; mi < 4; mi++) {
            #pragma unroll
            for (int nf = 0; nf < 4; nf++)
                acc[mi][nf] = __builtin_amdgcn_mfma_f32_16x16x32_bf16(
                    af1[mi], bf1[nf], acc[mi][nf], 0, 0, 0);
        }
        __builtin_amdgcn_s_setprio(0);
    }

    // epilogue: C/D layout col=lane&15, row=(lane>>4)*4+j  (verified)
    const int ccolb = n0 + wc * 64 + l15;
    float bv[4];
    #pragma unroll
    for (int nf = 0; nf < 4; nf++) bv[nf] = bias[ccolb + nf * 16];

    const int rowb = (MODE == 0 ? m0 : rbase) + wr * 64 + (lane >> 4) * 4;
    #pragma unroll
    for (int mi = 0; mi < 4; mi++) {
        #pragma unroll
        for (int j = 0; j < 4; j++) {
            size_t roff = (size_t)(rowb + mi * 16 + j) * NTOT;
            #pragma unroll
            for (int nf = 0; nf < 4; nf++) {
                float v = acc[mi][nf][j] + bv[nf];
                if (MODE == 0) v = gelu_f(v);
                Cdst[roff + ccolb + nf * 16] = f2bf(v);
            }
        }
    }
}

// ---------------- combine: out[token] = g1*y[r1] + g2*y[r2] ----------------
__global__ void k_combine(const ushort* __restrict__ y,
                          const int* __restrict__ r1, const int* __restrict__ r2,
                          const float* __restrict__ g1, const float* __restrict__ g2,
                          float* __restrict__ out) {
    int t = blockIdx.x;
    int d = threadIdx.x;          // 192 threads, 4 floats each
    int a = r1[t], b = r2[t];
    float wa = g1[t], wb = g2[t];
    size_t opos;
    if (t < NDET) { int bb = t >> 10, s = t & 1023; opos = ((size_t)bb * 1280 + s) * 768; }
    else { int tt = t - NDET; int bb = tt >> 8, s = tt & 255; opos = ((size_t)bb * 1280 + 1024 + s) * 768; }
    int di = d * 4;
    float4 o = make_float4(0.f, 0.f, 0.f, 0.f);
    if (a >= 0) {
        uint2 v = *(const uint2*)(y + (size_t)a * 768 + di);
        o.x += wa * bf2f(v.x & 0xffffu); o.y += wa * bf2f(v.x >> 16);
        o.z += wa * bf2f(v.y & 0xffffu); o.w += wa * bf2f(v.y >> 16);
    }
    if (b >= 0) {
        uint2 v = *(const uint2*)(y + (size_t)b * 768 + di);
        o.x += wb * bf2f(v.x & 0xffffu); o.y += wb * bf2f(v.x >> 16);
        o.z += wb * bf2f(v.y & 0xffffu); o.w += wb * bf2f(v.y >> 16);
    }
    *(float4*)(out + opos + di) = o;
}

extern "C" void kernel_launch(void* const* d_in, const int* in_sizes, int n_in,
                              void* d_out, int out_size, void* d_ws, size_t ws_size,
                              hipStream_t stream) {
    const float* xd  = (const float*)d_in[0];
    const float* xc  = (const float*)d_in[1];
    const float* wrd = (const float*)d_in[2];
    const float* wrc = (const float*)d_in[3];
    const float* w1  = (const float*)d_in[4];
    const float* b1  = (const float*)d_in[5];
    const float* w2  = (const float*)d_in[6];
    const float* b2  = (const float*)d_in[7];
    float* out = (float*)d_out;

    size_t off = 0;
    char* base = (char*)d_ws;
    auto alloc = [&](size_t bytes) -> char* {
        char* r = base + off;
        off += (bytes + 255) & ~(size_t)255;
        return r;
    };
    ushort* xbf = (ushort*)alloc((size_t)NTOK * DMODEL * 2);
    ushort* w1t = (ushort*)alloc((size_t)NE * MLPDIM * DMODEL * 2);
    ushort* w2t = (ushort*)alloc((size_t)NE * DMODEL * MLPDIM * 2);
    ushort* y   = (ushort*)alloc((size_t)TOT_ROWS * DMODEL * 2);
    int*   slot_map = (int*)alloc((size_t)TOT_ROWS * 4);
    int*   e1 = (int*)alloc((size_t)NTOK * 4);
    int*   e2 = (int*)alloc((size_t)NTOK * 4);
    float* g1 = (float*)alloc((size_t)NTOK * 4);
    float* g2 = (float*)alloc((size_t)NTOK * 4);
    int*   r1 = (int*)alloc((size_t)NTOK * 4);
    int*   r2 = (int*)alloc((size_t)NTOK * 4);

    // pick the largest expert-chunk whose h buffer fits the workspace
    const size_t h_per_e = (size_t)ROWS_PER_E * MLPDIM * 2;   // 31.5 MB
    int chunkE = 0;
    for (int c = NE; c >= 2; c >>= 1)
        if (off + c * h_per_e <= ws_size) { chunkE = c; break; }
    if (!chunkE) return;
    ushort* h = (ushort*)alloc((size_t)chunkE * h_per_e);

    hipMemsetAsync(slot_map, 0xFF, (size_t)TOT_ROWS * 4, stream);   // -1 = empty

    k_router<<<NTOK / 4, 256, 0, stream>>>(xd, xc, wrd, wrc, xbf, e1, e2, g1, g2);
    k_transpose_bf<<<dim3(MLPDIM / 32, DMODEL / 32, NE), dim3(8, 32), 0, stream>>>(w1, w1t, DMODEL, MLPDIM);
    k_transpose_bf<<<dim3(DMODEL / 32, MLPDIM / 32, NE), dim3(8, 32), 0, stream>>>(w2, w2t, MLPDIM, DMODEL);
    k_scan<<<24, 64, 0, stream>>>(e1, e2, slot_map, r1, r2);

    for (int e0 = 0; e0 < NE; e0 += chunkE) {
        int nmb1 = chunkE * (ROWS_PER_E / 256);              // 256-row m-blocks (GEMM1)
        k_gemm<256, DMODEL, MLPDIM, 0, true><<<nmb1 * (MLPDIM / 128), 512, 0, stream>>>(
            xbf, slot_map, w1t, b1, h, e0, 10);              // A-group: 10*384KB <= 4MB
        int nmb2 = chunkE * (ROWS_PER_E / 128);              // 128-row m-blocks (GEMM2)
        k_gemm<128, MLPDIM, DMODEL, 1, true><<<nmb2 * (DMODEL / 128), 256, 0, stream>>>(
            h, slot_map, w2t, b2, y, e0, 5);                 // A-group: 5*768KB <= 4MB
    }

    k_combine<<<NTOK, 192, 0, stream>>>(y, r1, r2, g1, g2, out);
}

// Round 20
// 565.596 us; speedup vs baseline: 1.0265x; 1.0265x over previous
//
#include <hip/hip_runtime.h>
#include <cstdint>
#include <cstddef>

#define NE 8
#define DMODEL 768
#define MLPDIM 3072
#define NDET 16384
#define NCLS 4096
#define NTOK 20480
#define ROWS_PER_E 5120   /* 16*256 (det) + 8*128 (cls) */
#define TOT_ROWS 40960

typedef float f32x4 __attribute__((ext_vector_type(4)));
typedef __bf16 bf16x8 __attribute__((ext_vector_type(8)));

__device__ __forceinline__ unsigned short f2bf(float f) {
    unsigned u = __float_as_uint(f);
    u += 0x7FFFu + ((u >> 16) & 1u);   // RNE
    return (unsigned short)(u >> 16);
}
__device__ __forceinline__ float bf2f(unsigned v) {
    return __uint_as_float(v << 16);
}
__device__ __forceinline__ float gelu_f(float x) {
    // jax.nn.gelu approximate=True. Exact identity: 0.5*(1+tanh(u)) == sigmoid(2u)
    // => gelu = x / (1 + exp(-2u)), u = 0.79788456*(x + 0.044715 x^3).
    float u = x * (0.7978845608028654f + 0.0356774081099f * x * x);
    return x * __frcp_rn(1.0f + __expf(-2.0f * u));
}

// async global->LDS, 16B per lane; dst is wave-uniform base, HW adds lane*16
__device__ __forceinline__ void gload16(const void* g, void* l) {
    __builtin_amdgcn_global_load_lds(
        (const __attribute__((address_space(1))) unsigned int*)g,
        (__attribute__((address_space(3))) unsigned int*)l, 16, 0, 0);
}

// ---------------- router (fp32) + x->bf16 conversion fused ----------------
__global__ void k_router(const float* __restrict__ xd, const float* __restrict__ xc,
                         const float* __restrict__ wrd, const float* __restrict__ wrc,
                         ushort* __restrict__ xbf,
                         int* __restrict__ e1, int* __restrict__ e2,
                         float* __restrict__ g1, float* __restrict__ g2) {
    int wave = threadIdx.x >> 6, lane = threadIdx.x & 63;
    int t = blockIdx.x * 4 + wave;
    if (t >= NTOK) return;
    const float* xrow;
    const float* w;
    if (t < NDET) { xrow = xd + (size_t)t * DMODEL; w = wrd; }
    else          { xrow = xc + (size_t)(t - NDET) * DMODEL; w = wrc; }
    ushort* xbrow = xbf + (size_t)t * DMODEL;
    float acc[8];
    #pragma unroll
    for (int e = 0; e < 8; e++) acc[e] = 0.0f;
    #pragma unroll
    for (int kk = 0; kk < DMODEL / 64; kk++) {
        int k = kk * 64 + lane;
        float xv = xrow[k];
        xbrow[k] = f2bf(xv);              // fused bf16 conversion
        const float* wr = w + k * 8;
        #pragma unroll
        for (int e = 0; e < 8; e++) acc[e] += xv * wr[e];
    }
    #pragma unroll
    for (int e = 0; e < 8; e++) {
        #pragma unroll
        for (int off = 32; off > 0; off >>= 1) acc[e] += __shfl_xor(acc[e], off);
    }
    // top-2 with lower-index tie-break (lax.top_k)
    int i1 = 0; float v1 = acc[0];
    #pragma unroll
    for (int e = 1; e < 8; e++) if (acc[e] > v1) { v1 = acc[e]; i1 = e; }
    int i2 = -1; float v2 = -1e30f;
    #pragma unroll
    for (int e = 0; e < 8; e++) if (e != i1 && acc[e] > v2) { v2 = acc[e]; i2 = e; }
    float Z = 0.0f;
    #pragma unroll
    for (int e = 0; e < 8; e++) Z += __expf(acc[e] - v1);
    if (lane == 0) {
        e1[t] = i1; e2[t] = i2;
        g1[t] = 1.0f / Z;
        g2[t] = __expf(v2 - v1) / Z;
    }
}

// ---------------- w [E][K][N] fp32 -> [E][N][K] bf16 (float4 loads) ----------------
__global__ void k_transpose_bf(const float* __restrict__ in, ushort* __restrict__ out,
                               int K, int N) {
    __shared__ float tile[32][33];
    int e = blockIdx.z;
    const float* A = in + (size_t)e * K * N;
    ushort* B = out + (size_t)e * N * K;
    int n0 = blockIdx.x * 32, k0 = blockIdx.y * 32;
    int tx = threadIdx.x, ty = threadIdx.y;   // (8,32)
    float4 v = *(const float4*)(A + (size_t)(k0 + ty) * N + n0 + tx * 4);
    tile[ty][tx * 4 + 0] = v.x; tile[ty][tx * 4 + 1] = v.y;
    tile[ty][tx * 4 + 2] = v.z; tile[ty][tx * 4 + 3] = v.w;
    __syncthreads();
    ushort4 o;
    o.x = f2bf(tile[tx * 4 + 0][ty]);
    o.y = f2bf(tile[tx * 4 + 1][ty]);
    o.z = f2bf(tile[tx * 4 + 2][ty]);
    o.w = f2bf(tile[tx * 4 + 3][ty]);
    *(ushort4*)(B + (size_t)(n0 + ty) * K + k0 + tx * 4) = o;
}

// ---------------- capacity scan: one wave per group, k-major order ----------------
__global__ void k_scan(const int* __restrict__ e1, const int* __restrict__ e2,
                       int* __restrict__ slot_map, int* __restrict__ r1, int* __restrict__ r2) {
    int g = blockIdx.x;          // 0..15 det, 16..23 cls
    int lane = threadIdx.x;      // 64 threads
    int S, C, base;
    if (g < 16) { S = 1024; C = 256; base = g * 1024; }
    else        { S = 512;  C = 128; base = NDET + (g - 16) * 512; }
    int cnt[8];
    #pragma unroll
    for (int e = 0; e < 8; e++) cnt[e] = 0;
    unsigned long long lower = (lane == 0) ? 0ULL : ((~0ULL) >> (64 - lane));
    int nch = (2 * S) >> 6;
    for (int ch = 0; ch < nch; ch++) {
        int n = ch * 64 + lane;
        int k = (n >= S) ? 1 : 0;
        int s = n - k * S;
        int tok = base + s;
        int e = k ? e2[tok] : e1[tok];
        int pos = 0;
        #pragma unroll
        for (int ee = 0; ee < 8; ee++) {
            unsigned long long m = __ballot(e == ee);
            if (e == ee) pos = cnt[ee] + __popcll(m & lower);
            cnt[ee] += __popcll(m);
        }
        int r = -1;
        if (pos < C) {
            int local = (g < 16) ? (g * 256 + pos) : (4096 + (g - 16) * 128 + pos);
            r = e * ROWS_PER_E + local;
            slot_map[r] = tok;
        }
        if (k == 0) r1[tok] = r; else r2[tok] = r;
    }
}

// ---------------- GEMM: 128x128 tile, BK=64, 4 waves, per-wave 64x64 ----------------
// Final configuration — best measured across 19 rounds (567us total, twice
// confirmed; 126us/GEMM dispatch = 767 TF, MfmaUtil ~34%, 0 bank conflicts).
// - 16x16x32 MFMA, per-wave 64x64 (LDS-roofline optimal for 4-wave blocks)
// - XOR-8 both-sides swizzle (pre-swizzled global source for global_load_lds,
//   same XOR on ds_read) — measured 0 conflicts
// - MFAST grouped m-fastest walk on BOTH GEMMs: A-group <= 4MB per-XCD L2
//   (GEMM1 gm=20 x 192KB, GEMM2 gm=5 x 768KB) -> FETCH 195->144MB measured
// - bijective XCD-chunked blockIdx swizzle; sigmoid-form gelu (exact identity)
// Loop: bar(drain); read kc0; MFMA kc0; read kc1; bar; ISSUE(ks+1); MFMA kc1.
// (Rejected by measurement: 256^2 tiles, BK=32 dbuf, counted-vmcnt pipelines,
//  free-run schedule, 32x32x16 MFMA, nt-stores, atomic scatter, 8-wave BM=256.)
// MODE 0: A = xbf gathered via slot_map -> h=gelu(A@B+b) (chunk-local rows)
// MODE 1: A = h (chunk-local) -> y[global row] = A@B+b
template<int KTOT, int NTOT, int MODE, bool MFAST>
__global__ __launch_bounds__(256, 4) void k_gemm(
    const ushort* __restrict__ Asrc, const int* __restrict__ slot_map,
    const ushort* __restrict__ wtBase, const float* __restrict__ biasBase,
    ushort* __restrict__ Cdst, int eBase, int gm) {
    constexpr int KT = KTOT / 64;            // 12 (GEMM1) / 48 (GEMM2)
    constexpr int NBN = NTOT / 128;
    __shared__ __align__(1024) ushort As[128 * 64];   // 16 KB
    __shared__ __align__(1024) ushort Bs[128 * 64];   // 16 KB

    // bijective XCD-chunked swizzle (gridDim.x % 8 == 0)
    const int q = gridDim.x >> 3;
    const int id2 = (blockIdx.x & 7) * q + (blockIdx.x >> 3);
    int mb, nb;
    if (MFAST) {
        // grouped m-fastest: group = gm consecutive mbs; within group, mb fastest
        int bpg = gm * NBN;
        int g = id2 / bpg, r = id2 - g * bpg;
        nb = r / gm;
        mb = g * gm + (r - nb * gm);
    } else {
        mb = id2 / NBN;
        nb = id2 - mb * NBN;
    }
    const int e = eBase + mb / (ROWS_PER_E / 128);
    const int m0 = mb * 128;                     // chunk-local row base
    const int rbase = eBase * ROWS_PER_E + m0;   // global expert-row base
    const int n0 = nb * 128;
    const ushort* Bt = wtBase + (size_t)e * KTOT * NTOT;
    const float* bias = biasBase + (size_t)e * NTOT;

    const int t = threadIdx.x, lane = t & 63, wave = t >> 6;
    const int g8 = lane >> 3;          // row within 8-row staging group
    const int p8 = lane & 7;           // physical 16B chunk this lane fills
    const int swz = ((p8 ^ g8) << 4);  // byte offset of LOGICAL chunk to fetch

    // staging: wave w covers A rows [w*32,w*32+32) and B rows [w*32,w*32+32),
    // 8 rows per gload -> 4 A-gloads + 4 B-gloads per wave per K-tile
    const char* aS[4];
    const char* bS[4];
    #pragma unroll
    for (int j = 0; j < 4; j++) {
        int r = wave * 32 + j * 8 + g8;
        size_t arow;
        if (MODE == 0) { int tk = slot_map[rbase + r]; arow = (size_t)(tk < 0 ? 0 : tk); }
        else           { arow = (size_t)(m0 + r); }
        aS[j] = (const char*)(Asrc + arow * KTOT) + swz;
        bS[j] = (const char*)(Bt + (size_t)(n0 + r) * KTOT) + swz;
    }

    auto ISSUE = [&](int kt) {
        size_t o = (size_t)kt * 128;   // 64 bf16 = 128 B per row per K-tile
        #pragma unroll
        for (int j = 0; j < 4; j++) {
            gload16(aS[j] + o, As + (wave * 32 + j * 8) * 64);
            gload16(bS[j] + o, Bs + (wave * 32 + j * 8) * 64);
        }
    };

    const int wr = wave >> 1, wc = wave & 1;   // wave grid 2(m) x 2(n), out 64x64
    const int l15 = lane & 15, kq = lane >> 4, l7 = lane & 7;
    const int ch[2] = { ((kq) ^ l7) << 3, ((4 + kq) ^ l7) << 3 };  // swizzled k-chunks

    f32x4 acc[4][4] = {};

    ISSUE(0);
    for (int ks = 0; ks < KT; ks++) {
        __syncthreads();               // drains vmcnt: tile ks visible in LDS
        // ---- kc = 0 ----
        bf16x8 af0[4], bf0[4];
        #pragma unroll
        for (int mi = 0; mi < 4; mi++)
            af0[mi] = *(const bf16x8*)(&As[(wr * 64 + mi * 16 + l15) * 64 + ch[0]]);
        #pragma unroll
        for (int nf = 0; nf < 4; nf++)
            bf0[nf] = *(const bf16x8*)(&Bs[(wc * 64 + nf * 16 + l15) * 64 + ch[0]]);
        __builtin_amdgcn_s_setprio(1);
        #pragma unroll
        for (int mi = 0; mi < 4; mi++) {
            #pragma unroll
            for (int nf = 0; nf < 4; nf++)
                acc[mi][nf] = __builtin_amdgcn_mfma_f32_16x16x32_bf16(
                    af0[mi], bf0[nf], acc[mi][nf], 0, 0, 0);
        }
        __builtin_amdgcn_s_setprio(0);
        // ---- kc = 1 ----
        bf16x8 af1[4], bf1[4];
        #pragma unroll
        for (int mi = 0; mi < 4; mi++)
            af1[mi] = *(const bf16x8*)(&As[(wr * 64 + mi * 16 + l15) * 64 + ch[1]]);
        #pragma unroll
        for (int nf = 0; nf < 4; nf++)
            bf1[nf] = *(const bf16x8*)(&Bs[(wc * 64 + nf * 16 + l15) * 64 + ch[1]]);
        __syncthreads();               // all waves done reading LDS tile ks
        if (ks + 1 < KT) ISSUE(ks + 1);   // loads fly under kc1 MFMA + other blocks
        __builtin_amdgcn_s_setprio(1);
        #pragma unroll
        for (int mi = 0; mi < 4; mi++) {
            #pragma unroll
            for (int nf = 0; nf < 4; nf++)
                acc[mi][nf] = __builtin_amdgcn_mfma_f32_16x16x32_bf16(
                    af1[mi], bf1[nf], acc[mi][nf], 0, 0, 0);
        }
        __builtin_amdgcn_s_setprio(0);
    }

    // epilogue: C/D layout col=lane&15, row=(lane>>4)*4+j  (verified)
    const int ccolb = n0 + wc * 64 + l15;
    float bv[4];
    #pragma unroll
    for (int nf = 0; nf < 4; nf++) bv[nf] = bias[ccolb + nf * 16];

    const int rowb = (MODE == 0 ? m0 : rbase) + wr * 64 + (lane >> 4) * 4;
    #pragma unroll
    for (int mi = 0; mi < 4; mi++) {
        #pragma unroll
        for (int j = 0; j < 4; j++) {
            size_t roff = (size_t)(rowb + mi * 16 + j) * NTOT;
            #pragma unroll
            for (int nf = 0; nf < 4; nf++) {
                float v = acc[mi][nf][j] + bv[nf];
                if (MODE == 0) v = gelu_f(v);
                Cdst[roff + ccolb + nf * 16] = f2bf(v);
            }
        }
    }
}

// ---------------- combine: out[token] = g1*y[r1] + g2*y[r2] ----------------
__global__ void k_combine(const ushort* __restrict__ y,
                          const int* __restrict__ r1, const int* __restrict__ r2,
                          const float* __restrict__ g1, const float* __restrict__ g2,
                          float* __restrict__ out) {
    int t = blockIdx.x;
    int d = threadIdx.x;          // 192 threads, 4 floats each
    int a = r1[t], b = r2[t];
    float wa = g1[t], wb = g2[t];
    size_t opos;
    if (t < NDET) { int bb = t >> 10, s = t & 1023; opos = ((size_t)bb * 1280 + s) * 768; }
    else { int tt = t - NDET; int bb = tt >> 8, s = tt & 255; opos = ((size_t)bb * 1280 + 1024 + s) * 768; }
    int di = d * 4;
    float4 o = make_float4(0.f, 0.f, 0.f, 0.f);
    if (a >= 0) {
        uint2 v = *(const uint2*)(y + (size_t)a * 768 + di);
        o.x += wa * bf2f(v.x & 0xffffu); o.y += wa * bf2f(v.x >> 16);
        o.z += wa * bf2f(v.y & 0xffffu); o.w += wa * bf2f(v.y >> 16);
    }
    if (b >= 0) {
        uint2 v = *(const uint2*)(y + (size_t)b * 768 + di);
        o.x += wb * bf2f(v.x & 0xffffu); o.y += wb * bf2f(v.x >> 16);
        o.z += wb * bf2f(v.y & 0xffffu); o.w += wb * bf2f(v.y >> 16);
    }
    *(float4*)(out + opos + di) = o;
}

extern "C" void kernel_launch(void* const* d_in, const int* in_sizes, int n_in,
                              void* d_out, int out_size, void* d_ws, size_t ws_size,
                              hipStream_t stream) {
    const float* xd  = (const float*)d_in[0];
    const float* xc  = (const float*)d_in[1];
    const float* wrd = (const float*)d_in[2];
    const float* wrc = (const float*)d_in[3];
    const float* w1  = (const float*)d_in[4];
    const float* b1  = (const float*)d_in[5];
    const float* w2  = (const float*)d_in[6];
    const float* b2  = (const float*)d_in[7];
    float* out = (float*)d_out;

    size_t off = 0;
    char* base = (char*)d_ws;
    auto alloc = [&](size_t bytes) -> char* {
        char* r = base + off;
        off += (bytes + 255) & ~(size_t)255;
        return r;
    };
    ushort* xbf = (ushort*)alloc((size_t)NTOK * DMODEL * 2);
    ushort* w1t = (ushort*)alloc((size_t)NE * MLPDIM * DMODEL * 2);
    ushort* w2t = (ushort*)alloc((size_t)NE * DMODEL * MLPDIM * 2);
    ushort* y   = (ushort*)alloc((size_t)TOT_ROWS * DMODEL * 2);
    int*   slot_map = (int*)alloc((size_t)TOT_ROWS * 4);
    int*   e1 = (int*)alloc((size_t)NTOK * 4);
    int*   e2 = (int*)alloc((size_t)NTOK * 4);
    float* g1 = (float*)alloc((size_t)NTOK * 4);
    float* g2 = (float*)alloc((size_t)NTOK * 4);
    int*   r1 = (int*)alloc((size_t)NTOK * 4);
    int*   r2 = (int*)alloc((size_t)NTOK * 4);

    // pick the largest expert-chunk whose h buffer fits the workspace
    const size_t h_per_e = (size_t)ROWS_PER_E * MLPDIM * 2;   // 31.5 MB
    int chunkE = 0;
    for (int c = NE; c >= 2; c >>= 1)
        if (off + c * h_per_e <= ws_size) { chunkE = c; break; }
    if (!chunkE) return;
    ushort* h = (ushort*)alloc((size_t)chunkE * h_per_e);

    hipMemsetAsync(slot_map, 0xFF, (size_t)TOT_ROWS * 4, stream);   // -1 = empty

    k_router<<<NTOK / 4, 256, 0, stream>>>(xd, xc, wrd, wrc, xbf, e1, e2, g1, g2);
    k_transpose_bf<<<dim3(MLPDIM / 32, DMODEL / 32, NE), dim3(8, 32), 0, stream>>>(w1, w1t, DMODEL, MLPDIM);
    k_transpose_bf<<<dim3(DMODEL / 32, MLPDIM / 32, NE), dim3(8, 32), 0, stream>>>(w2, w2t, MLPDIM, DMODEL);
    k_scan<<<24, 64, 0, stream>>>(e1, e2, slot_map, r1, r2);

    for (int e0 = 0; e0 < NE; e0 += chunkE) {
        int nmb = chunkE * (ROWS_PER_E / 128);               // 128-row m-blocks in chunk
        int gm1 = (nmb % 20 == 0) ? 20 : 10;                 // GEMM1 A-group: 20*192KB <= 4MB
        k_gemm<DMODEL, MLPDIM, 0, true><<<nmb * (MLPDIM / 128), 256, 0, stream>>>(
            xbf, slot_map, w1t, b1, h, e0, gm1);
        k_gemm<MLPDIM, DMODEL, 1, true><<<nmb * (DMODEL / 128), 256, 0, stream>>>(
            h, slot_map, w2t, b2, y, e0, 5);                 // GEMM2 A-group: 5*768KB <= 4MB
    }

    k_combine<<<NTOK, 192, 0, stream>>>(y, r1, r2, g1, g2, out);
}